// Round 6
// baseline (151.159 us; speedup 1.0000x reference)
//
#include <hip/hip_runtime.h>
#include <math.h>

#define NQ   8192      // N queries per batch
#define NP   8192      // M points per batch
#define NPH  4096      // points per half (per wave)
#define NF   128       // feature dim
#define NOUT 512       // output dim
#define NB   2         // batches
#define KNN  10
#define BNQ  (NB*NQ)   // 16384 total queries
#define QW   4         // queries per group (2 waves share them)

typedef unsigned long long u64;

__device__ __forceinline__ u64 shflup64(u64 v) {
  unsigned lo = (unsigned)__shfl_up((int)(unsigned)(v & 0xffffffffull), 1, 64);
  unsigned hi = (unsigned)__shfl_up((int)(unsigned)(v >> 32), 1, 64);
  return ((u64)hi << 32) | lo;
}

// d2 = ((q2+p2) + (-2qz)*pz) + (-2qy)*py + (-2qx)*px   (3 fma + 1 add), no clamp
__device__ __forceinline__ float dist2m(float m2x, float m2y, float m2z,
                                        float q2c, float4 p) {
  return fmaf(m2x, p.x, fmaf(m2y, p.y, fmaf(m2z, p.z, q2c + p.w)));
}

__device__ __forceinline__ float wmin64f(float v) {
#pragma unroll
  for (int off = 1; off < 64; off <<= 1)
    v = fminf(v, __shfl_xor(v, off, 64));
  return v;   // broadcast min across all 64 lanes
}

// Verified distributed sorted-insert (lanes 0..9 hold top-10 as u64 (d2|idx)).
// Candidates processed in ascending idx order; strict < vs theta is exact.
__device__ __forceinline__ void insert_loop(float d2, int idxbase, int lane,
                                            u64& lst, float& dlv, float& th) {
  for (;;) {
    u64 mask = __ballot(d2 < th);
    if (!mask) break;
    int src = __builtin_ctzll(mask);
    float cd = __uint_as_float(
        (unsigned)__builtin_amdgcn_readlane(__float_as_int(d2), src));
    cd = fmaxf(cd, 0.0f);               // clamp candidate (matches reference)
    u64 kk = ((u64)__float_as_uint(cd) << 32) | (unsigned)(idxbase + src);
    u64   prev  = shflup64(lst);
    float prevd = __shfl(dlv, lane - 1, 64);
    bool mylt = lst < kk;
    bool pins = (lane == 0) || (prev < kk);
    lst = mylt ? lst : (pins ? kk : prev);
    dlv = mylt ? dlv : (pins ? cd : prevd);
    th = fminf(th, __uint_as_float(
        (unsigned)__builtin_amdgcn_readlane(__float_as_int(dlv), 9)));
    if (lane == src) d2 = __builtin_nanf("");   // processed: leaves all ballots
  }
}

// ---------------------------------------------------------------------------
// Prep: pack points as (x,y,z,|p|^2) and transpose W[512][128] -> Wt[128][512]
// ---------------------------------------------------------------------------
__global__ __launch_bounds__(256) void prep_kernel(
    const float* __restrict__ gpcd, const float* __restrict__ W,
    float4* __restrict__ pts4, float* __restrict__ Wt)
{
  int tid = blockIdx.x * 256 + threadIdx.x;   // 0..65535
  if (tid < NB * NP) {
    const float* p = gpcd + (size_t)tid * 3;
    float x = p[0], y = p[1], z = p[2];
    float p2 = x * x + y * y + z * z;
    pts4[tid] = make_float4(x, y, z, p2);
  }
  int o = tid >> 7, f = tid & 127;
  Wt[(size_t)f * NOUT + o] = W[tid];
}

// ---------------------------------------------------------------------------
// Stage A+B, split-scan: 2 waves per 4-query group. Wave h scans points
// [h*4096, (h+1)*4096): pass 1 lane-min -> tau (10th-smallest lane-min,
// exact upper bound on half d_(10)) -> pass 2 tau-filtered insert = exact
// top-10 of the half. Halves merge exactly in LDS (rank = own index +
// count of other-list keys smaller; u64 keys globally unique). Wave h then
// does interp for queries {2h, 2h+1}.
// ---------------------------------------------------------------------------
__global__ __launch_bounds__(256) void knn_interp_kernel(
    const float* __restrict__ geometry, const float4* __restrict__ pts4,
    const float* __restrict__ features, float* __restrict__ At)
{
  __shared__ u64 cand[2][QW][2][12];    // [group][query][half][slot]
  __shared__ u64 merged[2][2][2][12];   // [group][half(owner)][local q][slot]

  const int lane = threadIdx.x & 63;
  const int wid  = threadIdx.x >> 6;    // 0..3
  const int g    = wid >> 1;            // query-group within block
  const int h    = wid & 1;             // half of the point set
  const int q0   = (blockIdx.x * 2 + g) * QW;
  const int b    = q0 >> 13;
  const float4* __restrict__ Ph = pts4 + ((size_t)b << 13) + (h << 12);
  const int hbase = h << 12;            // global idx offset of this half

  float m2x[QW], m2y[QW], m2z[QW], q2[QW];
#pragma unroll
  for (int j = 0; j < QW; ++j) {
    const float* gp = geometry + (size_t)(q0 + j) * 3;
    float x = gp[0], y = gp[1], z = gp[2];
    q2[j]  = x * x + y * y + z * z;
    m2x[j] = -2.0f * x; m2y[j] = -2.0f * y; m2z[j] = -2.0f * z;
  }

  // ---- pass 1: per-lane min over 64 points (2 per iter) ----
  float lmin[QW];
#pragma unroll
  for (int j = 0; j < QW; ++j) lmin[j] = INFINITY;
  for (int t = 0; t < NPH / 128; ++t) {
    const float4 pa = Ph[(t << 7) | lane];
    const float4 pb = Ph[(t << 7) | 64 | lane];
#pragma unroll
    for (int j = 0; j < QW; ++j)
      lmin[j] = fminf(lmin[j],
                      fminf(dist2m(m2x[j], m2y[j], m2z[j], q2[j], pa),
                            dist2m(m2x[j], m2y[j], m2z[j], q2[j], pb)));
  }
#pragma unroll
  for (int j = 0; j < QW; ++j) lmin[j] = fmaxf(lmin[j], 0.0f);

  // ---- tau = 10th-smallest lane-min; theta = tau + 1ulp ----
  float theta[QW];
#pragma unroll
  for (int j = 0; j < QW; ++j) {
    float lm  = lmin[j];
    float tau = 0.0f;
#pragma unroll
    for (int r = 0; r < KNN; ++r) {
      tau = wmin64f(lm);
      u64 mk = __ballot(lm == tau);
      int w  = __builtin_ctzll(mk);
      if (lane == w) lm = INFINITY;
    }
    theta[j] = __uint_as_float(__float_as_uint(tau) + 1);
  }

  u64   list[QW];
  float dl[QW];
#pragma unroll
  for (int j = 0; j < QW; ++j) {
    list[j] = 0x7F800000FFFFFFFFull;
    dl[j]   = INFINITY;
  }

  // ---- pass 2: exact filtered insert over the half ----
  for (int t = 0; t < NPH / 128; ++t) {
    const float4 pa = Ph[(t << 7) | lane];
    const float4 pb = Ph[(t << 7) | 64 | lane];
#pragma unroll
    for (int j = 0; j < QW; ++j) {
      float da = dist2m(m2x[j], m2y[j], m2z[j], q2[j], pa);
      insert_loop(da, hbase + (t << 7), lane, list[j], dl[j], theta[j]);
      float db = dist2m(m2x[j], m2y[j], m2z[j], q2[j], pb);
      insert_loop(db, hbase + (t << 7) + 64, lane, list[j], dl[j], theta[j]);
    }
  }

  // ---- publish half-lists ----
#pragma unroll
  for (int j = 0; j < QW; ++j)
    if (lane < KNN) cand[g][j][h][lane] = list[j];
  __syncthreads();

  // ---- exact merge of two sorted 10-lists (rank scatter) ----
#pragma unroll
  for (int jo = 0; jo < 2; ++jo) {
    const int jj = (h << 1) | jo;       // query this wave owns
    const bool isA = lane < KNN;
    const bool isB = (lane >= 16) && (lane < 16 + KNN);
    const int  li  = isA ? lane : lane - 16;
    if (isA | isB) {
      u64 key = cand[g][jj][isA ? 0 : 1][li];
      int pos = li;
#pragma unroll
      for (int m = 0; m < KNN; ++m) {
        u64 other = cand[g][jj][isA ? 1 : 0][m];
        pos += (other < key) ? 1 : 0;
      }
      if (pos < KNN) merged[g][h][jo][pos] = key;
    }
  }
  __syncthreads();

  // ---- weights + feature interpolation (2 queries per wave) ----
  const float* __restrict__ F = features + (size_t)b * NP * NF;
#pragma unroll
  for (int jo = 0; jo < 2; ++jo) {
    u64 k = merged[g][h][jo][lane < KNN ? lane : 0];
    float mdl = __uint_as_float((unsigned)(k >> 32));
    int  midx = (int)(unsigned)(k & 0xffffffffull);

    float w = 1.0f / (sqrtf(mdl) + 1e-8f);       // meaningful lanes 0..9
    float wsum = 0.0f;
#pragma unroll
    for (int jj2 = 0; jj2 < KNN; ++jj2) wsum += __shfl(w, jj2, 64);

    float a0 = 0.0f, a1 = 0.0f;
#pragma unroll
    for (int jj2 = 0; jj2 < KNN; ++jj2) {
      float wj = __shfl(w, jj2, 64) / wsum;
      int  mi  = __shfl(midx, jj2, 64);
      const float2 f2 = *(const float2*)(F + (size_t)mi * NF + (lane << 1));
      a0 = fmaf(wj, f2.x, a0);
      a1 = fmaf(wj, f2.y, a1);
    }
    const int q = q0 + (h << 1) + jo;
    At[(size_t)(lane << 1) * BNQ + q]       = a0;
    At[(size_t)((lane << 1) + 1) * BNQ + q] = a1;
  }
}

// ---------------------------------------------------------------------------
// Stage C: out[q][o] = sum_f At[f][q] * Wt[f][o] + bias[o]
// LDS-tiled: 64x64 block tile, KC=64 two-chunk, 4x4 per thread.
// ---------------------------------------------------------------------------
#define PKC  64
#define PLD  68

__global__ __launch_bounds__(256) void proj_kernel(
    const float* __restrict__ At, const float* __restrict__ Wt,
    const float* __restrict__ bias, float* __restrict__ out)
{
  __shared__ __align__(16) float lds_a[PKC][PLD];
  __shared__ __align__(16) float lds_b[PKC][PLD];

  const int mt = blockIdx.x & 255;
  const int ot = blockIdx.x >> 8;
  const int tx = threadIdx.x & 15;
  const int ty = threadIdx.x >> 4;
  const int m0 = mt << 6;
  const int o0 = ot << 6;

  const int lr = threadIdx.x >> 4;
  const int lc = (threadIdx.x & 15) << 2;

  float acc[4][4];
#pragma unroll
  for (int i = 0; i < 4; ++i)
#pragma unroll
    for (int jj = 0; jj < 4; ++jj) acc[i][jj] = 0.0f;

#pragma unroll
  for (int kc = 0; kc < NF / PKC; ++kc) {
    const int k0 = kc * PKC;
#pragma unroll
    for (int rp = 0; rp < 4; ++rp) {
      const int r = (rp << 4) + lr;
      const float4 a4 = *(const float4*)(At + (size_t)(k0 + r) * BNQ  + m0 + lc);
      const float4 b4 = *(const float4*)(Wt + (size_t)(k0 + r) * NOUT + o0 + lc);
      *(float4*)(&lds_a[r][lc]) = a4;
      *(float4*)(&lds_b[r][lc]) = b4;
    }
    __syncthreads();
#pragma unroll 8
    for (int k = 0; k < PKC; ++k) {
      const float4 a  = *(const float4*)(&lds_a[k][ty << 2]);
      const float4 bv = *(const float4*)(&lds_b[k][tx << 2]);
      float av[4] = {a.x, a.y, a.z, a.w};
      float bw[4] = {bv.x, bv.y, bv.z, bv.w};
#pragma unroll
      for (int i = 0; i < 4; ++i)
#pragma unroll
        for (int jj = 0; jj < 4; ++jj)
          acc[i][jj] = fmaf(av[i], bw[jj], acc[i][jj]);
    }
    __syncthreads();
  }

  const float4 bb = *(const float4*)(bias + o0 + (tx << 2));
  float bias4[4] = {bb.x, bb.y, bb.z, bb.w};
#pragma unroll
  for (int i = 0; i < 4; ++i) {
    float4 r;
    r.x = acc[i][0] + bias4[0];
    r.y = acc[i][1] + bias4[1];
    r.z = acc[i][2] + bias4[2];
    r.w = acc[i][3] + bias4[3];
    *(float4*)(out + (size_t)(m0 + (ty << 2) + i) * NOUT + o0 + (tx << 2)) = r;
  }
}

// ---------------------------------------------------------------------------
extern "C" void kernel_launch(void* const* d_in, const int* in_sizes, int n_in,
                              void* d_out, int out_size, void* d_ws, size_t ws_size,
                              hipStream_t stream) {
  const float* geometry = (const float*)d_in[0];   // [2,8192,3]
  const float* gpcd     = (const float*)d_in[1];   // [2,8192,3]
  const float* features = (const float*)d_in[2];   // [2,8192,128]
  const float* W        = (const float*)d_in[3];   // [512,128]
  const float* bias     = (const float*)d_in[4];   // [512]
  float* out = (float*)d_out;

  char*   ws   = (char*)d_ws;
  float*  At   = (float*)ws;                              // 128*16384 f32 = 8 MiB
  float4* pts4 = (float4*)(ws + (size_t)NF * BNQ * 4);    // 16384 * 16 B
  float*  Wt   = (float*)(ws + (size_t)NF * BNQ * 4 + (size_t)NB * NP * 16);

  prep_kernel<<<256, 256, 0, stream>>>(gpcd, W, pts4, Wt);
  knn_interp_kernel<<<BNQ / 8, 256, 0, stream>>>(geometry, pts4, features, At);
  proj_kernel<<<(BNQ / 64) * (NOUT / 64), 256, 0, stream>>>(At, Wt, bias, out);
}

// Round 7
// 144.649 us; speedup vs baseline: 1.0450x; 1.0450x over previous
//
#include <hip/hip_runtime.h>
#include <math.h>

#define NQ   8192      // N queries per batch
#define NP   8192      // M points per batch
#define NF   128       // feature dim
#define NOUT 512       // output dim
#define NB   2         // batches
#define KNN  10
#define BNQ  (NB*NQ)   // 16384 total queries
#define QW   4         // queries per wave

typedef unsigned long long u64;

__device__ __forceinline__ u64 shfl64(u64 v, int src) {
  unsigned lo = (unsigned)__shfl((int)(unsigned)(v & 0xffffffffull), src, 64);
  unsigned hi = (unsigned)__shfl((int)(unsigned)(v >> 32), src, 64);
  return ((u64)hi << 32) | lo;
}
__device__ __forceinline__ u64 shflup64(u64 v) {
  unsigned lo = (unsigned)__shfl_up((int)(unsigned)(v & 0xffffffffull), 1, 64);
  unsigned hi = (unsigned)__shfl_up((int)(unsigned)(v >> 32), 1, 64);
  return ((u64)hi << 32) | lo;
}

// Shifted distance for SELECTION: d2' = p2 - 2 q.p (3 fma). True d2 = d2'+q2.
// Order w.r.t. a fixed query is preserved (q2 is a per-query constant).
__device__ __forceinline__ float dist2s(float m2x, float m2y, float m2z,
                                        float4 p) {
  return fmaf(m2x, p.x, fmaf(m2y, p.y, fmaf(m2z, p.z, p.w)));
}

// Monotone f32->u32 bit map: mono(a) < mono(b) (unsigned)  <=>  a < b (float).
__device__ __forceinline__ unsigned fmono(float f) {
  unsigned u = __float_as_uint(f);
  return u ^ ((unsigned)((int)u >> 31) | 0x80000000u);
}

__device__ __forceinline__ float wmin64f(float v) {
#pragma unroll
  for (int off = 1; off < 64; off <<= 1)
    v = fminf(v, __shfl_xor(v, off, 64));
  return v;   // broadcast min across all 64 lanes
}

// Verified distributed sorted-insert (lanes 0..9 hold top-10; u64 key =
// (mono(d2')<<32)|idx so ordering is exact incl. negative shifted dists).
__device__ __forceinline__ void insert_loop(float d2, int idxbase, int lane,
                                            u64& lst, float& dlv, float& th) {
  for (;;) {
    u64 mask = __ballot(d2 < th);
    if (!mask) break;
    int src = __builtin_ctzll(mask);
    float cd = __uint_as_float(
        (unsigned)__builtin_amdgcn_readlane(__float_as_int(d2), src));
    u64 kk = ((u64)fmono(cd) << 32) | (unsigned)(idxbase + src);
    u64   prev  = shflup64(lst);
    float prevd = __shfl(dlv, lane - 1, 64);
    bool mylt = lst < kk;
    bool pins = (lane == 0) || (prev < kk);
    lst = mylt ? lst : (pins ? kk : prev);
    dlv = mylt ? dlv : (pins ? cd : prevd);
    th = fminf(th, __uint_as_float(
        (unsigned)__builtin_amdgcn_readlane(__float_as_int(dlv), 9)));
    if (lane == src) d2 = __builtin_nanf("");   // processed: leaves all ballots
  }
}

// ---------------------------------------------------------------------------
// Prep: pack points as (x,y,z,|p|^2) and transpose W[512][128] -> Wt[128][512]
// ---------------------------------------------------------------------------
__global__ __launch_bounds__(256) void prep_kernel(
    const float* __restrict__ gpcd, const float* __restrict__ W,
    float4* __restrict__ pts4, float* __restrict__ Wt)
{
  int tid = blockIdx.x * 256 + threadIdx.x;   // 0..65535
  if (tid < NB * NP) {
    const float* p = gpcd + (size_t)tid * 3;
    float x = p[0], y = p[1], z = p[2];
    float p2 = x * x + y * y + z * z;
    pts4[tid] = make_float4(x, y, z, p2);
  }
  int o = tid >> 7, f = tid & 127;
  Wt[(size_t)f * NOUT + o] = W[tid];
}

// ---------------------------------------------------------------------------
// Stage A+B: per-wave kNN (QW queries/wave) + inverse-distance interp.
// Pass 1: per-lane min of shifted d2' over its 128 points (4 pts/iter, MLP).
// tau = 10th-smallest lane-min (knockout); theta = nextup(tau).
// Pass 2: per-point pre-check (min over 4 queries vs thmax) gates the exact
// per-query tau-filtered distributed inserts.
// ---------------------------------------------------------------------------
__global__ __launch_bounds__(256) void knn_interp_kernel(
    const float* __restrict__ geometry, const float4* __restrict__ pts4,
    const float* __restrict__ features, float* __restrict__ At)
{
  const int lane = threadIdx.x & 63;
  const int wave = (blockIdx.x << 2) | (threadIdx.x >> 6);
  const int q0   = wave * QW;           // QW consecutive queries (same batch)
  const int b    = q0 >> 13;            // q0 / 8192
  const float4* __restrict__ P = pts4 + ((size_t)b << 13) + lane;

  float m2x[QW], m2y[QW], m2z[QW], q2[QW];
#pragma unroll
  for (int j = 0; j < QW; ++j) {
    const float* g = geometry + (size_t)(q0 + j) * 3;
    float x = g[0], y = g[1], z = g[2];
    q2[j]  = x * x + y * y + z * z;
    m2x[j] = -2.0f * x; m2y[j] = -2.0f * y; m2z[j] = -2.0f * z;
  }

  // ---- pass 1: per-lane min of shifted d2' (4 points per iteration) ----
  float lmin[QW];
#pragma unroll
  for (int j = 0; j < QW; ++j) lmin[j] = INFINITY;
  for (int t = 0; t < NP / 256; ++t) {
    float4 pv[4];
#pragma unroll
    for (int s = 0; s < 4; ++s) pv[s] = P[(t << 8) + (s << 6)];
#pragma unroll
    for (int j = 0; j < QW; ++j) {
      float d0 = dist2s(m2x[j], m2y[j], m2z[j], pv[0]);
      float d1 = dist2s(m2x[j], m2y[j], m2z[j], pv[1]);
      float d2 = dist2s(m2x[j], m2y[j], m2z[j], pv[2]);
      float d3 = dist2s(m2x[j], m2y[j], m2z[j], pv[3]);
      lmin[j] = fminf(lmin[j], fminf(fminf(d0, d1), fminf(d2, d3)));
    }
  }

  // ---- tau = 10th-smallest lane-min; theta = nextup(tau) (shifted domain) --
  float theta[QW];
#pragma unroll
  for (int j = 0; j < QW; ++j) {
    float lm  = lmin[j];
    float tau = 0.0f;
#pragma unroll
    for (int r = 0; r < KNN; ++r) {
      tau = wmin64f(lm);
      u64 mk = __ballot(lm == tau);
      int w  = __builtin_ctzll(mk);
      if (lane == w) lm = INFINITY;
    }
    unsigned tb = __float_as_uint(tau);
    unsigned nb = (tb & 0x80000000u) ? (tb == 0x80000000u ? 1u : tb - 1u)
                                     : tb + 1u;     // nextafter(tau, +inf)
    theta[j] = __uint_as_float(nb);
  }
  float thmax = fmaxf(fmaxf(theta[0], theta[1]), fmaxf(theta[2], theta[3]));

  u64   list[QW];
  float dl[QW];
#pragma unroll
  for (int j = 0; j < QW; ++j) {
    list[j] = 0xFF800000FFFFFFFFull;    // (mono(+inf), idx=~0)
    dl[j]   = INFINITY;
  }

  // ---- pass 2: pre-checked exact filtered insert (4 points/iter) ----
  for (int t = 0; t < NP / 256; ++t) {
    float4 pv[4];
#pragma unroll
    for (int s = 0; s < 4; ++s) pv[s] = P[(t << 8) + (s << 6)];
#pragma unroll
    for (int s = 0; s < 4; ++s) {
      float d[QW];
#pragma unroll
      for (int j = 0; j < QW; ++j)
        d[j] = dist2s(m2x[j], m2y[j], m2z[j], pv[s]);
      float pmin = fminf(fminf(d[0], d[1]), fminf(d[2], d[3]));
      if (__ballot(pmin < thmax)) {
#pragma unroll
        for (int j = 0; j < QW; ++j)
          insert_loop(d[j], (t << 8) + (s << 6), lane, list[j], dl[j], theta[j]);
        thmax = fmaxf(fmaxf(theta[0], theta[1]), fmaxf(theta[2], theta[3]));
      }
    }
  }

  // ---- weights + feature interpolation ----
  const float* __restrict__ F = features + (size_t)b * NP * NF;
#pragma unroll
  for (int j = 0; j < QW; ++j) {
    float td2 = fmaxf(dl[j] + q2[j], 0.0f);       // back to true d2, clamped
    float w   = 1.0f / (sqrtf(td2) + 1e-8f);      // meaningful on lanes 0..9
    float wsum = 0.0f;
#pragma unroll
    for (int jj = 0; jj < KNN; ++jj) wsum += __shfl(w, jj, 64);

    float a0 = 0.0f, a1 = 0.0f;
#pragma unroll
    for (int jj = 0; jj < KNN; ++jj) {
      float wj = __shfl(w, jj, 64) / wsum;
      int  mi  = (int)(unsigned)(shfl64(list[j], jj) & 0xffffffffull);
      const float2 f2 = *(const float2*)(F + (size_t)mi * NF + (lane << 1));
      a0 = fmaf(wj, f2.x, a0);
      a1 = fmaf(wj, f2.y, a1);
    }
    At[(size_t)(lane << 1) * BNQ + (q0 + j)]       = a0;
    At[(size_t)((lane << 1) + 1) * BNQ + (q0 + j)] = a1;
  }
}

// ---------------------------------------------------------------------------
// Stage C: out[q][o] = sum_f At[f][q] * Wt[f][o] + bias[o]
// LDS-tiled: 64x64 block tile, KC=64 two-chunk, 4x4 per thread.
// ---------------------------------------------------------------------------
#define PKC  64
#define PLD  68

__global__ __launch_bounds__(256) void proj_kernel(
    const float* __restrict__ At, const float* __restrict__ Wt,
    const float* __restrict__ bias, float* __restrict__ out)
{
  __shared__ __align__(16) float lds_a[PKC][PLD];
  __shared__ __align__(16) float lds_b[PKC][PLD];

  const int mt = blockIdx.x & 255;
  const int ot = blockIdx.x >> 8;
  const int tx = threadIdx.x & 15;
  const int ty = threadIdx.x >> 4;
  const int m0 = mt << 6;
  const int o0 = ot << 6;

  const int lr = threadIdx.x >> 4;
  const int lc = (threadIdx.x & 15) << 2;

  float acc[4][4];
#pragma unroll
  for (int i = 0; i < 4; ++i)
#pragma unroll
    for (int jj = 0; jj < 4; ++jj) acc[i][jj] = 0.0f;

#pragma unroll
  for (int kc = 0; kc < NF / PKC; ++kc) {
    const int k0 = kc * PKC;
#pragma unroll
    for (int rp = 0; rp < 4; ++rp) {
      const int r = (rp << 4) + lr;
      const float4 a4 = *(const float4*)(At + (size_t)(k0 + r) * BNQ  + m0 + lc);
      const float4 b4 = *(const float4*)(Wt + (size_t)(k0 + r) * NOUT + o0 + lc);
      *(float4*)(&lds_a[r][lc]) = a4;
      *(float4*)(&lds_b[r][lc]) = b4;
    }
    __syncthreads();
#pragma unroll 8
    for (int k = 0; k < PKC; ++k) {
      const float4 a  = *(const float4*)(&lds_a[k][ty << 2]);
      const float4 bv = *(const float4*)(&lds_b[k][tx << 2]);
      float av[4] = {a.x, a.y, a.z, a.w};
      float bw[4] = {bv.x, bv.y, bv.z, bv.w};
#pragma unroll
      for (int i = 0; i < 4; ++i)
#pragma unroll
        for (int jj = 0; jj < 4; ++jj)
          acc[i][jj] = fmaf(av[i], bw[jj], acc[i][jj]);
    }
    __syncthreads();
  }

  const float4 bb = *(const float4*)(bias + o0 + (tx << 2));
  float bias4[4] = {bb.x, bb.y, bb.z, bb.w};
#pragma unroll
  for (int i = 0; i < 4; ++i) {
    float4 r;
    r.x = acc[i][0] + bias4[0];
    r.y = acc[i][1] + bias4[1];
    r.z = acc[i][2] + bias4[2];
    r.w = acc[i][3] + bias4[3];
    *(float4*)(out + (size_t)(m0 + (ty << 2) + i) * NOUT + o0 + (tx << 2)) = r;
  }
}

// ---------------------------------------------------------------------------
extern "C" void kernel_launch(void* const* d_in, const int* in_sizes, int n_in,
                              void* d_out, int out_size, void* d_ws, size_t ws_size,
                              hipStream_t stream) {
  const float* geometry = (const float*)d_in[0];   // [2,8192,3]
  const float* gpcd     = (const float*)d_in[1];   // [2,8192,3]
  const float* features = (const float*)d_in[2];   // [2,8192,128]
  const float* W        = (const float*)d_in[3];   // [512,128]
  const float* bias     = (const float*)d_in[4];   // [512]
  float* out = (float*)d_out;

  char*   ws   = (char*)d_ws;
  float*  At   = (float*)ws;                              // 128*16384 f32 = 8 MiB
  float4* pts4 = (float4*)(ws + (size_t)NF * BNQ * 4);    // 16384 * 16 B
  float*  Wt   = (float*)(ws + (size_t)NF * BNQ * 4 + (size_t)NB * NP * 16);

  prep_kernel<<<256, 256, 0, stream>>>(gpcd, W, pts4, Wt);
  knn_interp_kernel<<<BNQ / (QW * 4), 256, 0, stream>>>(geometry, pts4, features, At);
  proj_kernel<<<(BNQ / 64) * (NOUT / 64), 256, 0, stream>>>(At, Wt, bias, out);
}